// Round 2
// baseline (197.600 us; speedup 1.0000x reference)
//
#include <hip/hip_runtime.h>
#include <hip/hip_bf16.h>

typedef short bf16x8 __attribute__((ext_vector_type(8)));
typedef float f32x4 __attribute__((ext_vector_type(4)));
typedef float f32x16 __attribute__((ext_vector_type(16)));
typedef unsigned uint2v __attribute__((ext_vector_type(2)));
typedef unsigned uint4v __attribute__((ext_vector_type(4)));

#define MFMA16(a, b, c) __builtin_amdgcn_mfma_f32_16x16x32_bf16((a), (b), (c), 0, 0, 0)
#define MFMA32(a, b, c) __builtin_amdgcn_mfma_f32_32x32x16_bf16((a), (b), (c), 0, 0, 0)

#if __has_builtin(__builtin_amdgcn_exp2f)
#define EXP2(x) __builtin_amdgcn_exp2f(x)
#else
#define EXP2(x) exp2f(x)
#endif

static constexpr int B_ = 2, S_ = 2048, D_ = 1024, H_ = 16, DH = 64;
static constexpr int M_ = B_ * S_;   // 4096
static constexpr int K_ = D_;        // 1024
static constexpr float kQS = 0.18033688011112042f;   // log2(e)/8, folded into Wq

static __device__ __forceinline__ ushort f2bf(float f) {
    __hip_bfloat16 h = __float2bfloat16(f);
    return *reinterpret_cast<ushort*>(&h);
}
static __device__ __forceinline__ float bf2f(ushort u) {
    __hip_bfloat16 h;
    *reinterpret_cast<ushort*>(&h) = u;
    return __bfloat162float(h);
}

static __device__ __forceinline__ void gload16(const ushort* g, ushort* l) {
    __builtin_amdgcn_global_load_lds((const __attribute__((address_space(1))) void*)g,
                                     (__attribute__((address_space(3))) void*)l, 16, 0, 0);
}

// pack two fp32 -> (bf16(hi) << 16) | bf16(lo), truncation (v_perm_b32)
static __device__ __forceinline__ unsigned pkbf(float lo, float hi) {
    return __builtin_amdgcn_perm(__builtin_bit_cast(unsigned, hi),
                                 __builtin_bit_cast(unsigned, lo), 0x07060302u);
}

// ---------------------------------------------------------------------------
// Prep: z=0..3 -> fused convert+transpose of the 4 weights (Wq pre-scaled by
// log2(e)/8); z=4 -> fp32->bf16 convert of x (4M elems, 16/thread).
// ---------------------------------------------------------------------------
__global__ __launch_bounds__(256) void prep5(const float* __restrict__ x,
                                             const float* __restrict__ W0,
                                             const float* __restrict__ W1,
                                             const float* __restrict__ W2,
                                             const float* __restrict__ W3,
                                             ushort* __restrict__ xb,
                                             ushort* __restrict__ T0,
                                             ushort* __restrict__ T1,
                                             ushort* __restrict__ T2,
                                             ushort* __restrict__ T3) {
    int z = blockIdx.z;
    int tx = threadIdx.x, ty = threadIdx.y;
    int t = ty * 32 + tx;
    if (z == 4) {
        int blk = blockIdx.y * 32 + blockIdx.x;      // 0..1023
#pragma unroll
        for (int k = 0; k < 4; k++) {
            int i = blk * 1024 + k * 256 + t;        // float4 id
            float4 v = reinterpret_cast<const float4*>(x)[i];
            ushort4 o;
            o.x = f2bf(v.x); o.y = f2bf(v.y); o.z = f2bf(v.z); o.w = f2bf(v.w);
            reinterpret_cast<ushort4*>(xb)[i] = o;
        }
        return;
    }
    __shared__ float tile[32][33];
    const float* W = (z == 0) ? W0 : (z == 1) ? W1 : (z == 2) ? W2 : W3;
    ushort* T = (z == 0) ? T0 : (z == 1) ? T1 : (z == 2) ? T2 : T3;
    float sc = (z == 0) ? kQS : 1.0f;
    int bx = blockIdx.x, by = blockIdx.y;
#pragma unroll
    for (int i = 0; i < 4; i++)
        tile[ty + i * 8][tx] = W[(by * 32 + ty + i * 8) * D_ + bx * 32 + tx];
    __syncthreads();
#pragma unroll
    for (int i = 0; i < 4; i++)
        T[(bx * 32 + ty + i * 8) * K_ + by * 32 + tx] = f2bf(tile[tx][ty + i * 8] * sc);
}

// ---------------------------------------------------------------------------
// m97-style GEMM (single-buffered), swapped-operand epilogues (r13, neutral
// but kept: vector stores). MODE 0 (TN=128): fused QKV; MODE 1 (TN=64): O-proj.
// ---------------------------------------------------------------------------
template <int MODE, int TN>
__global__ __launch_bounds__(256, 3) void gemm128(const ushort* __restrict__ A,
                                                  const ushort* __restrict__ Wt,
                                                  const float* __restrict__ bias_q,
                                                  const float* __restrict__ bias_k,
                                                  const float* __restrict__ bias_v,
                                                  ushort* __restrict__ Qb,
                                                  ushort* __restrict__ Kb,
                                                  ushort* __restrict__ Vtb,
                                                  float* __restrict__ outf) {
    constexpr int NJ = TN / 32;
    __shared__ __align__(16) ushort As[128 * 32];
    __shared__ __align__(16) ushort Bs[TN * 32];

    int m0 = blockIdx.x * 128;
    int n0 = blockIdx.y * TN;
    int t = threadIdx.x;
    int lane = t & 63, w = t >> 6;
    int ln = lane & 15, lq = lane >> 4;
    int wm = (w >> 1) * 64, wn = (w & 1) * (TN / 2);

    int c0 = t, c1 = t + 256;
    const ushort* Ag0 = A + (size_t)(m0 + (c0 >> 2)) * K_ + (c0 & 3) * 8;
    const ushort* Ag1 = A + (size_t)(m0 + (c1 >> 2)) * K_ + (c1 & 3) * 8;
    const ushort* Bg0 = Wt + (size_t)(n0 + (c0 >> 2)) * K_ + (c0 & 3) * 8;
    const ushort* Bg1 = Wt + (size_t)(n0 + (c1 >> 2)) * K_ + (c1 & 3) * 8;
    ushort* Al0 = As + c0 * 8;
    ushort* Al1 = As + c1 * 8;
    ushort* Bl0 = Bs + c0 * 8;
    ushort* Bl1 = Bs + c1 * 8;

    const bool swp = (MODE == 1) || (n0 < 2048);   // block-uniform

    f32x4 acc[4][NJ];
#pragma unroll
    for (int i = 0; i < 4; i++)
#pragma unroll
        for (int j = 0; j < NJ; j++) acc[i][j] = f32x4{0.f, 0.f, 0.f, 0.f};

    if (swp) {
        for (int k0 = 0; k0 < K_; k0 += 32) {
            gload16(Ag0 + k0, Al0);
            gload16(Ag1 + k0, Al1);
            gload16(Bg0 + k0, Bl0);
            if (TN == 128) gload16(Bg1 + k0, Bl1);
            __syncthreads();
            bf16x8 af[4], bfr[NJ];
#pragma unroll
            for (int i = 0; i < 4; i++)
                af[i] = *reinterpret_cast<const bf16x8*>(As + (wm + i * 16 + ln) * 32 + lq * 8);
#pragma unroll
            for (int j = 0; j < NJ; j++)
                bfr[j] = *reinterpret_cast<const bf16x8*>(Bs + (wn + j * 16 + ln) * 32 + lq * 8);
#pragma unroll
            for (int i = 0; i < 4; i++)
#pragma unroll
                for (int j = 0; j < NJ; j++)
                    acc[i][j] = MFMA16(bfr[j], af[i], acc[i][j]);   // swapped
            __syncthreads();
        }
    } else {
        for (int k0 = 0; k0 < K_; k0 += 32) {
            gload16(Ag0 + k0, Al0);
            gload16(Ag1 + k0, Al1);
            gload16(Bg0 + k0, Bl0);
            if (TN == 128) gload16(Bg1 + k0, Bl1);
            __syncthreads();
            bf16x8 af[4], bfr[NJ];
#pragma unroll
            for (int i = 0; i < 4; i++)
                af[i] = *reinterpret_cast<const bf16x8*>(As + (wm + i * 16 + ln) * 32 + lq * 8);
#pragma unroll
            for (int j = 0; j < NJ; j++)
                bfr[j] = *reinterpret_cast<const bf16x8*>(Bs + (wn + j * 16 + ln) * 32 + lq * 8);
#pragma unroll
            for (int i = 0; i < 4; i++)
#pragma unroll
                for (int j = 0; j < NJ; j++)
                    acc[i][j] = MFMA16(af[i], bfr[j], acc[i][j]);
            __syncthreads();
        }
    }

    if (MODE == 1) {
#pragma unroll
        for (int j = 0; j < NJ; j++) {
            int nb = n0 + wn + j * 16 + lq * 4;
            float4 bv4 = *reinterpret_cast<const float4*>(bias_q + nb);
#pragma unroll
            for (int i = 0; i < 4; i++) {
                int m = m0 + wm + i * 16 + ln;
                float4 o;
                o.x = acc[i][j][0] + bv4.x;
                o.y = acc[i][j][1] + bv4.y;
                o.z = acc[i][j][2] + bv4.z;
                o.w = acc[i][j][3] + bv4.w;
                *reinterpret_cast<float4*>(outf + (size_t)m * D_ + nb) = o;
            }
        }
    } else if (n0 < 2048) {
        int which = n0 >> 10;
        const float* bp = which ? bias_k : bias_q;
        ushort* dst = which ? Kb : Qb;
        float bsc = which ? 1.0f : kQS;
#pragma unroll
        for (int j = 0; j < NJ; j++) {
            int nb = ((n0 + wn + j * 16) & 1023) + lq * 4;
            int h = nb >> 6, dhb = nb & 63;
            float4 bv4 = *reinterpret_cast<const float4*>(bp + nb);
            bv4.x *= bsc; bv4.y *= bsc; bv4.z *= bsc; bv4.w *= bsc;
#pragma unroll
            for (int i = 0; i < 4; i++) {
                int m = m0 + wm + i * 16 + ln;
                int b = m >> 11, s = m & 2047;
                ushort4 o4;
                o4.x = f2bf(acc[i][j][0] + bv4.x);
                o4.y = f2bf(acc[i][j][1] + bv4.y);
                o4.z = f2bf(acc[i][j][2] + bv4.z);
                o4.w = f2bf(acc[i][j][3] + bv4.w);
                *reinterpret_cast<ushort4*>(dst + (((size_t)(b * H_ + h) * S_) + s) * DH + dhb) = o4;
            }
        }
    } else {
#pragma unroll
        for (int j = 0; j < NJ; j++) {
            int n = n0 + wn + j * 16 + ln;
            int nn = n & 1023, h = nn >> 6, dh = nn & 63;
            float bv = bias_v[nn];
#pragma unroll
            for (int i = 0; i < 4; i++) {
                int m = m0 + wm + i * 16 + lq * 4;
                int b = m >> 11, s0 = m & 2047;
                ushort4 o4;
                o4.x = f2bf(acc[i][j][0] + bv);
                o4.y = f2bf(acc[i][j][1] + bv);
                o4.z = f2bf(acc[i][j][2] + bv);
                o4.w = f2bf(acc[i][j][3] + bv);
                *reinterpret_cast<ushort4*>(Vtb + (((size_t)(b * H_ + h) * DH) + dh) * S_ + s0) = o4;
            }
        }
    }
}

// ---------------------------------------------------------------------------
// Flash attention v9b: 32x32x16 MFMA + fully in-register P (no Pl LDS buffer)
// + double-buffered K/V with ONE barrier per iter (stage-next-before-compute).
//
// Per wave: one 32-q tile, 16 iters x 64 keys (K-split x2 as in v8).
// Swapped QK (S^T = K.Q^T, 32x32): lane (ln=lane&31, hi=lane>>5) holds, for
// q = ln, the 16 keys key(r) = (r&3)+8*(r>>2)+4*hi. exp2 -> truncating pack
// (pkbf, v8 numerics) -> permlane32_swap (HW: vdst.row1 <-> src.row0, i.e.
// lanes32-63 of 1st arg swap with lanes0-31 of 2nd; m214 T12 recipe pairing
// swap(pk[2i], pk[2i+4])) builds the PV A-frags entirely in-register:
//   s = swap(pk[0], pk[2]) -> s.x = [own pk0 ; peer pk2] = frag word0
//                             s.y = [peer pk0 ; own pk2] = frag word2
// l via ones-MFMA on the SAME truncated frags (v8 semantics); its 32x32
// D-layout gives every lane all 16 of its q-rows' sums -> shuffle-free
// epilogue. Per iter/wave: 20 MFMA32 (8 QK + 4 l + 8 PV), 16 ds_read_b128,
// 0 P LDS traffic, 0 bank conflicts by construction. LDS = 2*(8K+8V) =
// 32 KB -> 4 blocks/CU, 16 waves/CU kept.
// ---------------------------------------------------------------------------
__global__ __launch_bounds__(256, 4) void attn32(const ushort* __restrict__ Q,
                                                 const ushort* __restrict__ K,
                                                 const ushort* __restrict__ Vt,
                                                 ushort* __restrict__ O1,
                                                 ushort* __restrict__ O2,
                                                 float* __restrict__ L) {
    __shared__ __align__(16) ushort Kl[2][4096];   // [buf][8 dhgrp][64 key][8 dh]
    __shared__ __align__(16) ushort Vl[2][4096];   // [buf][8 keygrp][64 dh][8 key]

    int bid = blockIdx.x;
    int half = bid >> 9;        // K-half
    int rem = bid & 511;
    int qb = rem & 15;          // 16 q-blocks of 128 rows
    int bh = rem >> 4;          // b*H + h
    int t = threadIdx.x;
    int lane = t & 63, w = t >> 6;
    int ln = lane & 31, hi = lane >> 5;
    int q0 = qb * 128 + w * 32;

    const ushort* Qp = Q + (size_t)bh * S_ * DH;
    const ushort* Kp = K + (size_t)bh * S_ * DH + (size_t)half * 1024 * DH;
    const ushort* Vp = Vt + (size_t)bh * DH * S_ + (size_t)half * 1024;

    // Q fragments (B-operand): col = q = ln, k = dh = ks*16 + hi*8 + j
    bf16x8 qf[4];
#pragma unroll
    for (int ks = 0; ks < 4; ks++)
        qf[ks] = *reinterpret_cast<const bf16x8*>(Qp + (size_t)(q0 + ln) * DH + ks * 16 + hi * 8);

    bf16x8 ones;
#pragma unroll
    for (int j = 0; j < 8; j++) ones[j] = (short)0x3F80;   // bf16 1.0

    // staging: chunk c <-> (key/dh = c&63, group = c>>6), linear LDS dest
    int c0 = t, c1 = t + 256;
    const ushort* Kg0 = Kp + (size_t)(c0 & 63) * DH + (c0 >> 6) * 8;
    const ushort* Kg1 = Kp + (size_t)(c1 & 63) * DH + (c1 >> 6) * 8;
    const ushort* Vg0 = Vp + (size_t)(c0 & 63) * S_ + (c0 >> 6) * 8;
    const ushort* Vg1 = Vp + (size_t)(c1 & 63) * S_ + (c1 >> 6) * 8;

    f32x16 o_acc[2];            // [dh-half][16 q-rows]
    f32x16 l_acc;               // truncated-P row sums (v8 semantics)
#pragma unroll
    for (int r = 0; r < 16; r++) { o_acc[0][r] = 0.f; o_acc[1][r] = 0.f; l_acc[r] = 0.f; }

    // prologue: stage tile 0 into buffer 0
    gload16(Kg0, &Kl[0][c0 * 8]);
    gload16(Kg1, &Kl[0][c1 * 8]);
    gload16(Vg0, &Vl[0][c0 * 8]);
    gload16(Vg1, &Vl[0][c1 * 8]);

    for (int kt = 0; kt < 16; kt++) {
        int cur = kt & 1;
        __syncthreads();        // buf[cur] staged (barrier drains vmcnt) + buf[cur^1] reads done
        if (kt < 15) {          // stage NEXT tile under this iter's compute
            int kb = (kt + 1) * 64;
            gload16(Kg0 + (size_t)kb * DH, &Kl[cur ^ 1][c0 * 8]);
            gload16(Kg1 + (size_t)kb * DH, &Kl[cur ^ 1][c1 * 8]);
            gload16(Vg0 + kb, &Vl[cur ^ 1][c0 * 8]);
            gload16(Vg1 + kb, &Vl[cur ^ 1][c1 * 8]);
        }
        const ushort* Kc = Kl[cur];
        const ushort* Vc = Vl[cur];
#pragma unroll
        for (int kb2 = 0; kb2 < 2; kb2++) {        // two 32-key blocks
            // ---- S^T = K.Q^T (32x32): A = K rows=keys, B = Q cols=q ----
            f32x16 sc;
#pragma unroll
            for (int r = 0; r < 16; r++) sc[r] = 0.f;
#pragma unroll
            for (int ks = 0; ks < 4; ks++) {
                bf16x8 kf = *reinterpret_cast<const bf16x8*>(
                    Kc + (ks * 2 + hi) * 512 + (kb2 * 32 + ln) * 8);
                sc = MFMA32(kf, qf[ks], sc);
            }
            // ---- exp2 + truncating pack: pk[j] = (p[2j+1]<<16)|p[2j] ----
            unsigned pk[8];
#pragma unroll
            for (int j = 0; j < 8; j++)
                pk[j] = pkbf(EXP2(sc[2 * j]), EXP2(sc[2 * j + 1]));
            // ---- permlane32_swap (vdst.row1 <-> src.row0) -> PV A-frags ----
            // s.x = [arg0.row0 ; arg1.row0], s.y = [arg0.row1 ; arg1.row1]
            uint2v s0 = __builtin_amdgcn_permlane32_swap(pk[0], pk[2], false, false);
            uint2v s1 = __builtin_amdgcn_permlane32_swap(pk[1], pk[3], false, false);
            uint2v s2 = __builtin_amdgcn_permlane32_swap(pk[4], pk[6], false, false);
            uint2v s3 = __builtin_amdgcn_permlane32_swap(pk[5], pk[7], false, false);
            bf16x8 f0 = __builtin_bit_cast(bf16x8, (uint4v){s0.x, s1.x, s0.y, s1.y});  // keys 0..15
            bf16x8 f1 = __builtin_bit_cast(bf16x8, (uint4v){s2.x, s3.x, s2.y, s3.y});  // keys 16..31
            // ---- l: rowsum of the SAME truncated frags (ones-MFMA) ----
            l_acc = MFMA32(f0, ones, l_acc);
            l_acc = MFMA32(f1, ones, l_acc);
            // ---- PV: B = V^T frags, col=dh, k=key ----
#pragma unroll
            for (int h2 = 0; h2 < 2; h2++) {
                bf16x8 v0 = *reinterpret_cast<const bf16x8*>(
                    Vc + (kb2 * 4 + hi) * 512 + (h2 * 32 + ln) * 8);
                bf16x8 v1 = *reinterpret_cast<const bf16x8*>(
                    Vc + (kb2 * 4 + 2 + hi) * 512 + (h2 * 32 + ln) * 8);
                o_acc[h2] = MFMA32(f0, v0, o_acc[h2]);
                o_acc[h2] = MFMA32(f1, v1, o_acc[h2]);
            }
        }
    }

    // ---- epilogue: normalized partial + l (rows = (r&3)+8*(r>>2)+4*hi) ----
    ushort* Op = half ? O2 : O1;
    float* Lp = L + ((size_t)half * 32 + bh) * S_;
    int b = bh >> 4, h = bh & 15;
    if (ln == 0) {
#pragma unroll
        for (int r = 0; r < 16; r++)
            Lp[q0 + (r & 3) + 8 * (r >> 2) + 4 * hi] = l_acc[r];
    }
#pragma unroll
    for (int r = 0; r < 16; r++) {
        int s = q0 + (r & 3) + 8 * (r >> 2) + 4 * hi;
        float linv = 1.0f / l_acc[r];
        size_t base = (((size_t)(b * S_ + s)) * H_ + h) * DH;
        Op[base + ln] = f2bf(o_acc[0][r] * linv);
        Op[base + 32 + ln] = f2bf(o_acc[1][r] * linv);
    }
}

// ---------------------------------------------------------------------------
// Combine the two K-half partials: AO = (l1*O1n + l2*O2n)/(l1+l2), bf16.
// ---------------------------------------------------------------------------
__global__ __launch_bounds__(256) void attn_comb(const ushort* __restrict__ O1,
                                                 const ushort* __restrict__ O2,
                                                 const float* __restrict__ L,
                                                 ushort* __restrict__ AO) {
    int i = blockIdx.x * 256 + threadIdx.x;    // 8-elem group id
    int row = i >> 7;           // (b*S+s)
    int col = (i & 127) * 8;
    int h = col >> 6;
    int b = row >> 11, s = row & 2047;
    int bh = b * 16 + h;
    float l1 = L[(size_t)bh * S_ + s];
    float l2 = L[((size_t)32 + bh) * S_ + s];
    float inv = 1.0f / (l1 + l2);
    float w1 = l1 * inv, w2 = l2 * inv;
    size_t off = (size_t)row * D_ + col;
    ushort4 a0 = reinterpret_cast<const ushort4*>(O1 + off)[0];
    ushort4 a1 = reinterpret_cast<const ushort4*>(O1 + off)[1];
    ushort4 b0 = reinterpret_cast<const ushort4*>(O2 + off)[0];
    ushort4 b1 = reinterpret_cast<const ushort4*>(O2 + off)[1];
    ushort4 o0, o1v;
    o0.x = f2bf(w1 * bf2f(a0.x) + w2 * bf2f(b0.x));
    o0.y = f2bf(w1 * bf2f(a0.y) + w2 * bf2f(b0.y));
    o0.z = f2bf(w1 * bf2f(a0.z) + w2 * bf2f(b0.z));
    o0.w = f2bf(w1 * bf2f(a0.w) + w2 * bf2f(b0.w));
    o1v.x = f2bf(w1 * bf2f(a1.x) + w2 * bf2f(b1.x));
    o1v.y = f2bf(w1 * bf2f(a1.y) + w2 * bf2f(b1.y));
    o1v.z = f2bf(w1 * bf2f(a1.z) + w2 * bf2f(b1.z));
    o1v.w = f2bf(w1 * bf2f(a1.w) + w2 * bf2f(b1.w));
    reinterpret_cast<ushort4*>(AO + off)[0] = o0;
    reinterpret_cast<ushort4*>(AO + off)[1] = o1v;
}

// ---------------------------------------------------------------------------
extern "C" void kernel_launch(void* const* d_in, const int* in_sizes, int n_in,
                              void* d_out, int out_size, void* d_ws, size_t ws_size,
                              hipStream_t stream) {
    const float* x  = (const float*)d_in[0];
    const float* Wq = (const float*)d_in[1];
    const float* bq = (const float*)d_in[2];
    const float* Wk = (const float*)d_in[3];
    const float* bk = (const float*)d_in[4];
    const float* Wv = (const float*)d_in[5];
    const float* bv = (const float*)d_in[6];
    const float* Wo = (const float*)d_in[7];
    const float* bo = (const float*)d_in[8];
    float* out = (float*)d_out;

    char* ws = (char*)d_ws;
    const size_t MB = 1024 * 1024;
    ushort* wtq = (ushort*)(ws + 0 * MB);    // [3072,1024] fused q,k,v contiguous
    ushort* wtk = (ushort*)(ws + 2 * MB);
    ushort* wtv = (ushort*)(ws + 4 * MB);
    ushort* wto = (ushort*)(ws + 6 * MB);
    ushort* xb  = (ushort*)(ws + 8 * MB);    // bf16 x [M,K]; dead after QKV
    ushort* Qb  = (ushort*)(ws + 16 * MB);   // [B,H,S,Dh] (pre-scaled by kQS)
    ushort* Kb  = (ushort*)(ws + 24 * MB);   // [B,H,S,Dh]
    ushort* Vtb = (ushort*)(ws + 32 * MB);   // [B,H,Dh,S]
    ushort* AO  = (ushort*)(ws + 40 * MB);   // [B,S,D] bf16
    ushort* O1  = (ushort*)(ws + 8 * MB);    // half-0 partial (reuses xb)
    ushort* O2  = (ushort*)(ws + 48 * MB);   // half-1 partial
    float*  Lw  = (float*)(ws + 56 * MB);    // l partials [2][32][S]

    // prep: 4 weight transposes (z=0..3) + x convert (z=4)
    prep5<<<dim3(32, 32, 5), dim3(32, 8), 0, stream>>>(
        x, Wq, Wk, Wv, Wo, xb, wtq, wtk, wtv, wto);

    // fused QKV projection: N = 3072, 128x128 tiles -> 768 blocks = 3/CU
    gemm128<0, 128><<<dim3(M_ / 128, 3072 / 128), 256, 0, stream>>>(
        xb, wtq, bq, bk, bv, Qb, Kb, Vtb, nullptr);

    // attention v9b: 32x32 MFMA, in-register P, double-buffered K/V
    attn32<<<1024, 256, 0, stream>>>(Qb, Kb, Vtb, O1, O2, Lw);
    attn_comb<<<(M_ * D_ / 8) / 256, 256, 0, stream>>>(O1, O2, Lw, AO);

    // output projection: N = 1024, 128x64 tiles -> 512 blocks = 2/CU
    gemm128<1, 64><<<dim3(M_ / 128, D_ / 64), 256, 0, stream>>>(
        AO, wto, bo, nullptr, nullptr, nullptr, nullptr, nullptr, out);
}